// Round 1
// baseline (3414.928 us; speedup 1.0000x reference)
//
#include <hip/hip_runtime.h>
#include <hip/hip_bf16.h>

// GPT forward: V=32000 D=1024 S=1024 L=4 H=16 DK=DV=64 B=4 DFF=4096
#define V_   32000
#define D_   1024
#define S_   1024
#define L_   4
#define H_   16
#define B_   4
#define DFF_ 4096
#define M_   (B_*S_)   // 4096 token rows

using bf_t = __hip_bfloat16;
typedef __bf16 bf16x8 __attribute__((ext_vector_type(8)));
typedef float  f32x4  __attribute__((ext_vector_type(4)));

#define AS1(p) ((__attribute__((address_space(1))) void*)(p))
#define AS3(p) ((__attribute__((address_space(3))) void*)(p))

// ---------------------------------------------------------------------------
// Transpose f32 [R,C] -> bf16 [C,R], batched over two strides (z = z1*n2+z2)
// ---------------------------------------------------------------------------
__global__ __launch_bounds__(256) void k_transpose_bf16(
    const float* __restrict__ src, bf_t* __restrict__ dst,
    int R, int C, long srcS1, long srcS2, long dstS1, long dstS2, int n2)
{
  const int z  = blockIdx.z;
  const int z1 = z / n2, z2 = z % n2;
  src += (size_t)z1 * srcS1 + (size_t)z2 * srcS2;
  dst += (size_t)z1 * dstS1 + (size_t)z2 * dstS2;
  __shared__ float tile[32][33];
  const int c0 = blockIdx.x * 32, r0 = blockIdx.y * 32;
  const int lx = threadIdx.x, ly = threadIdx.y;  // 32 x 8
  #pragma unroll
  for (int i = 0; i < 32; i += 8)
    tile[ly + i][lx] = src[(size_t)(r0 + ly + i) * C + (c0 + lx)];
  __syncthreads();
  #pragma unroll
  for (int i = 0; i < 32; i += 8)
    dst[(size_t)(c0 + ly + i) * R + (r0 + lx)] = __float2bfloat16(tile[lx][ly + i]);
}

// ---------------------------------------------------------------------------
// Embedding: x[b,s,:] = tok_emb[idx[b,s],:] + pos_emb[s,:]
// ---------------------------------------------------------------------------
__global__ __launch_bounds__(256) void k_embed(
    const int* __restrict__ idx, const float* __restrict__ tok,
    const float* __restrict__ pos, float* __restrict__ x)
{
  const int row = blockIdx.x;          // b*S + s
  const int s   = row & (S_ - 1);
  const int t   = idx[row];
  const float4* tr = (const float4*)(tok + (size_t)t * D_);
  const float4* pr = (const float4*)(pos + (size_t)s * D_);
  float4* xr = (float4*)(x + (size_t)row * D_);
  const int i = threadIdx.x;           // 256 threads * float4 = 1024 floats
  float4 a = tr[i], b = pr[i];
  xr[i] = make_float4(a.x + b.x, a.y + b.y, a.z + b.z, a.w + b.w);
}

// ---------------------------------------------------------------------------
// LayerNorm (f32 in) -> bf16 out.  One block (256 thr) per row, D=1024.
// ---------------------------------------------------------------------------
__global__ __launch_bounds__(256) void k_ln(
    const float* __restrict__ x, const float* __restrict__ g,
    const float* __restrict__ bb, bf_t* __restrict__ out)
{
  __shared__ float red[8];
  const int row = blockIdx.x, tid = threadIdx.x;
  const float4 v = ((const float4*)(x + (size_t)row * D_))[tid];
  float s = v.x + v.y + v.z + v.w;
  #pragma unroll
  for (int o = 32; o > 0; o >>= 1) s += __shfl_down(s, o);
  if ((tid & 63) == 0) red[tid >> 6] = s;
  __syncthreads();
  const float mu = (red[0] + red[1] + red[2] + red[3]) * (1.f / D_);
  const float dx = v.x - mu, dy = v.y - mu, dz = v.z - mu, dw = v.w - mu;
  float ss = dx*dx + dy*dy + dz*dz + dw*dw;
  #pragma unroll
  for (int o = 32; o > 0; o >>= 1) ss += __shfl_down(ss, o);
  if ((tid & 63) == 0) red[4 + (tid >> 6)] = ss;
  __syncthreads();
  const float var = (red[4] + red[5] + red[6] + red[7]) * (1.f / D_);
  const float rs  = rsqrtf(var + 1e-5f);
  const float4 gv = ((const float4*)g)[tid];
  const float4 bv = ((const float4*)bb)[tid];
  const size_t base = (size_t)row * D_ + tid * 4;
  out[base + 0] = __float2bfloat16(dx * rs * gv.x + bv.x);
  out[base + 1] = __float2bfloat16(dy * rs * gv.y + bv.y);
  out[base + 2] = __float2bfloat16(dz * rs * gv.z + bv.z);
  out[base + 3] = __float2bfloat16(dw * rs * gv.w + bv.w);
}

// ---------------------------------------------------------------------------
// bf16 MFMA GEMM: C[M,N] = A[M,K] * Bt[N,K]^T  (+bias +residual, relu, out f32/bf16)
// m97 structure: 128x128 tile, BK=64, 4 waves (2x2 of 64x64), 16x16x32 MFMA,
// global_load_lds width=16, linear LDS, 2 barriers per K-step.
// Grid: (N/128, M/128), block 256.
// ---------------------------------------------------------------------------
template<bool HAS_BIAS, bool RELU, bool RESID, bool OUT_BF16>
__global__ __launch_bounds__(256) void k_gemm(
    const bf_t* __restrict__ A, const bf_t* __restrict__ Bt,
    float* outF, bf_t* outB,
    const float* __restrict__ bias, const float* resid,
    int N, int K)
{
  __shared__ __bf16 As[128 * 64];
  __shared__ __bf16 Bs[128 * 64];
  const int tid  = threadIdx.x;
  const int lane = tid & 63, wid = tid >> 6;
  const int n0 = blockIdx.x * 128, m0 = blockIdx.y * 128;
  f32x4 acc[4][4] = {};

  const int srow = lane >> 3;        // 0..7 within 8-row chunk
  const int scol = (lane & 7) * 8;   // k-element offset (16B)
  const int mw = (wid >> 1) * 64, nw = (wid & 1) * 64;

  for (int kt = 0; kt < K; kt += 64) {
    #pragma unroll
    for (int i = 0; i < 4; ++i) {
      const int chunk = i * 4 + wid;           // wave-uniform
      const int r = chunk * 8 + srow;
      const bf_t* sa = A  + (size_t)(m0 + r) * K + kt + scol;
      const bf_t* sb = Bt + (size_t)(n0 + r) * K + kt + scol;
      __builtin_amdgcn_global_load_lds(AS1(sa), AS3(&As[chunk * 512]), 16, 0, 0);
      __builtin_amdgcn_global_load_lds(AS1(sb), AS3(&Bs[chunk * 512]), 16, 0, 0);
    }
    asm volatile("s_waitcnt vmcnt(0)" ::: "memory");
    __syncthreads();
    #pragma unroll
    for (int kk = 0; kk < 2; ++kk) {
      bf16x8 af[4], bfr[4];
      #pragma unroll
      for (int mi = 0; mi < 4; ++mi)
        af[mi] = *(const bf16x8*)&As[(mw + mi * 16 + (lane & 15)) * 64 + kk * 32 + (lane >> 4) * 8];
      #pragma unroll
      for (int ni = 0; ni < 4; ++ni)
        bfr[ni] = *(const bf16x8*)&Bs[(nw + ni * 16 + (lane & 15)) * 64 + kk * 32 + (lane >> 4) * 8];
      #pragma unroll
      for (int mi = 0; mi < 4; ++mi)
        #pragma unroll
        for (int ni = 0; ni < 4; ++ni)
          acc[mi][ni] = __builtin_amdgcn_mfma_f32_16x16x32_bf16(af[mi], bfr[ni], acc[mi][ni], 0, 0, 0);
    }
    __syncthreads();
  }

  // epilogue — C/D layout: col = lane&15, row = (lane>>4)*4 + j  [verified]
  const int cr = (lane >> 4) * 4, cc = lane & 15;
  #pragma unroll
  for (int mi = 0; mi < 4; ++mi) {
    #pragma unroll
    for (int ni = 0; ni < 4; ++ni) {
      const int col = n0 + nw + ni * 16 + cc;
      const float bv = HAS_BIAS ? bias[col] : 0.f;
      #pragma unroll
      for (int j = 0; j < 4; ++j) {
        const int row = m0 + mw + mi * 16 + cr + j;
        float v = acc[mi][ni][j] + bv;
        if (RESID) v += resid[(size_t)row * N + col];
        if (RELU)  v = fmaxf(v, 0.f);
        if (OUT_BF16) outB[(size_t)row * N + col] = __float2bfloat16(v);
        else          outF[(size_t)row * N + col] = v;
      }
    }
  }
}

// ---------------------------------------------------------------------------
// Flash attention, f32 vector. qkv layout: [B*S, 3072] (Q|K|V per head inline).
// Block = 256 thr (4 waves), one (b,h), 64 query rows. 64-key LDS tiles,
// online softmax. Pitches: K/V=65 (b32 conflict-free), sc=68 (b128-aligned).
// Grid: (S/64, B*H).
// ---------------------------------------------------------------------------
__global__ __launch_bounds__(256) void k_attn(
    const float* __restrict__ qkv, bf_t* __restrict__ o)
{
  __shared__ float Qs[64 * 64];
  __shared__ float Ks[64 * 65];
  __shared__ float Vs[64 * 65];
  __shared__ float sc[64 * 68];
  __shared__ float mst[64], lst[64], corr[64];

  const int qt = blockIdx.x, bh = blockIdx.y;
  const int b = bh >> 4, h = bh & 15;
  const int tid = threadIdx.x, lane = tid & 63, wid = tid >> 6;
  const int qbase = qt * 64;
  const int r0 = wid * 16;     // this wave's 16 rows
  const int d  = lane;         // this lane's output dim

  // stage Q (prescaled by 1/sqrt(64))
  #pragma unroll
  for (int p = 0; p < 4; ++p) {
    const int r = p * 16 + (tid >> 4);
    const int c = (tid & 15) * 4;
    const float4 v = *(const float4*)(qkv + (size_t)(b * S_ + qbase + r) * 3072 + h * 64 + c);
    Qs[r * 64 + c + 0] = v.x * 0.125f;
    Qs[r * 64 + c + 1] = v.y * 0.125f;
    Qs[r * 64 + c + 2] = v.z * 0.125f;
    Qs[r * 64 + c + 3] = v.w * 0.125f;
  }
  if (tid < 64) { mst[tid] = -1e30f; lst[tid] = 0.f; }

  float oacc[16];
  #pragma unroll
  for (int i = 0; i < 16; ++i) oacc[i] = 0.f;

  const int ntiles = qt + 1;   // causal: only tiles with t0 <= qbase+63
  for (int kt = 0; kt < ntiles; ++kt) {
    __syncthreads();           // protect Ks/Vs/sc from prev-iter readers
    #pragma unroll
    for (int p = 0; p < 4; ++p) {
      const int r = p * 16 + (tid >> 4);
      const int c = (tid & 15) * 4;
      const size_t rowoff = (size_t)(b * S_ + kt * 64 + r) * 3072 + h * 64 + c;
      const float4 kv = *(const float4*)(qkv + rowoff + 1024);
      const float4 vv = *(const float4*)(qkv + rowoff + 2048);
      Ks[r * 65 + c + 0] = kv.x; Ks[r * 65 + c + 1] = kv.y;
      Ks[r * 65 + c + 2] = kv.z; Ks[r * 65 + c + 3] = kv.w;
      Vs[r * 65 + c + 0] = vv.x; Vs[r * 65 + c + 1] = vv.y;
      Vs[r * 65 + c + 2] = vv.z; Vs[r * 65 + c + 3] = vv.w;
    }
    __syncthreads();

    // scores: wave covers rows r0..r0+15, lane = key t
    {
      const int t = lane;
      float acc[16];
      #pragma unroll
      for (int i = 0; i < 16; ++i) acc[i] = 0.f;
      for (int d4 = 0; d4 < 16; ++d4) {
        const float k0 = Ks[t * 65 + d4 * 4 + 0];
        const float k1 = Ks[t * 65 + d4 * 4 + 1];
        const float k2 = Ks[t * 65 + d4 * 4 + 2];
        const float k3 = Ks[t * 65 + d4 * 4 + 3];
        #pragma unroll
        for (int i = 0; i < 16; ++i) {
          const float4 q4 = *(const float4*)&Qs[(r0 + i) * 64 + d4 * 4];
          acc[i] = fmaf(q4.x, k0, acc[i]);
          acc[i] = fmaf(q4.y, k1, acc[i]);
          acc[i] = fmaf(q4.z, k2, acc[i]);
          acc[i] = fmaf(q4.w, k3, acc[i]);
        }
      }
      const int tglob = kt * 64 + t;
      #pragma unroll
      for (int i = 0; i < 16; ++i)
        sc[(r0 + i) * 68 + t] = (tglob <= qbase + r0 + i) ? acc[i] : -1e30f;
    }
    __syncthreads();

    // online softmax update: thread -> (r = tid>>2, tq = tid&3)
    {
      const int r = tid >> 2, tq = tid & 3;
      float mloc = -1e30f;
      #pragma unroll
      for (int i = 0; i < 16; ++i) mloc = fmaxf(mloc, sc[r * 68 + tq + i * 4]);
      mloc = fmaxf(mloc, __shfl_xor(mloc, 1));
      mloc = fmaxf(mloc, __shfl_xor(mloc, 2));
      const float mold = mst[r];
      const float mnew = fmaxf(mold, mloc);
      float ssum = 0.f;
      #pragma unroll
      for (int i = 0; i < 16; ++i) {
        const int ix = r * 68 + tq + i * 4;
        const float p_ = __expf(sc[ix] - mnew);
        sc[ix] = p_;
        ssum += p_;
      }
      ssum += __shfl_xor(ssum, 1);
      ssum += __shfl_xor(ssum, 2);
      if (tq == 0) {
        corr[r] = __expf(mold - mnew);
        lst[r]  = lst[r] * corr[r] + ssum;
        mst[r]  = mnew;
      }
    }
    __syncthreads();

    // PV accumulate: wave rows r0..r0+15, lane = dim d
    #pragma unroll
    for (int i = 0; i < 16; ++i) oacc[i] *= corr[r0 + i];
    for (int t4 = 0; t4 < 16; ++t4) {
      const float v0 = Vs[(t4 * 4 + 0) * 65 + d];
      const float v1 = Vs[(t4 * 4 + 1) * 65 + d];
      const float v2 = Vs[(t4 * 4 + 2) * 65 + d];
      const float v3 = Vs[(t4 * 4 + 3) * 65 + d];
      #pragma unroll
      for (int i = 0; i < 16; ++i) {
        const float4 p4 = *(const float4*)&sc[(r0 + i) * 68 + t4 * 4];
        oacc[i] = fmaf(p4.x, v0, oacc[i]);
        oacc[i] = fmaf(p4.y, v1, oacc[i]);
        oacc[i] = fmaf(p4.z, v2, oacc[i]);
        oacc[i] = fmaf(p4.w, v3, oacc[i]);
      }
    }
  }
  __syncthreads();
  #pragma unroll
  for (int i = 0; i < 16; ++i) {
    const float inv = 1.f / lst[r0 + i];
    o[(size_t)(b * S_ + qbase + r0 + i) * 1024 + h * 64 + d] =
        __float2bfloat16(oacc[i] * inv);
  }
}

// ---------------------------------------------------------------------------
extern "C" void kernel_launch(void* const* d_in, const int* in_sizes, int n_in,
                              void* d_out, int out_size, void* d_ws, size_t ws_size,
                              hipStream_t stream)
{
  (void)in_sizes; (void)n_in; (void)out_size; (void)ws_size;
  const int*   idx  = (const int*)  d_in[0];
  const float* tok  = (const float*)d_in[1];
  const float* pos  = (const float*)d_in[2];
  const float* wq   = (const float*)d_in[3];
  const float* wk   = (const float*)d_in[4];
  const float* wv   = (const float*)d_in[5];
  const float* wo   = (const float*)d_in[6];
  const float* w1   = (const float*)d_in[7];
  const float* b1   = (const float*)d_in[8];
  const float* w2   = (const float*)d_in[9];
  const float* b2   = (const float*)d_in[10];
  const float* ln1g = (const float*)d_in[11];
  const float* ln1b = (const float*)d_in[12];
  const float* ln2g = (const float*)d_in[13];
  const float* ln2b = (const float*)d_in[14];
  const float* lnfg = (const float*)d_in[15];
  const float* lnfb = (const float*)d_in[16];
  const float* lmw  = (const float*)d_in[17];
  const float* lmb  = (const float*)d_in[18];
  float* out = (float*)d_out;

  // workspace carve-up (~284 MB)
  char* ws = (char*)d_ws;
  size_t off = 0;
  auto alloc = [&](size_t bytes) {
    void* p = ws + off; off += (bytes + 255) & ~(size_t)255; return p;
  };
  bf_t*  qkvw = (bf_t*) alloc((size_t)L_ * 3072 * 1024 * 2);  // Bt [3072][1024] per layer
  bf_t*  wot  = (bf_t*) alloc((size_t)L_ * 1024 * 1024 * 2);  // Bt [1024][1024]
  bf_t*  w1t  = (bf_t*) alloc((size_t)L_ * 4096 * 1024 * 2);  // Bt [4096][1024]
  bf_t*  w2t  = (bf_t*) alloc((size_t)L_ * 1024 * 4096 * 2);  // Bt [1024][4096]
  bf_t*  lmwt = (bf_t*) alloc((size_t)V_ * 1024 * 2);         // Bt [32000][1024]
  float* x    = (float*)alloc((size_t)M_ * D_ * 4);
  bf_t*  hbuf = (bf_t*) alloc((size_t)M_ * D_ * 2);
  float* qkv  = (float*)alloc((size_t)M_ * 3072 * 4);
  bf_t*  attb = (bf_t*) alloc((size_t)M_ * D_ * 2);
  bf_t*  ffnb = (bf_t*) alloc((size_t)M_ * DFF_ * 2);

  const dim3 tb(32, 8);
  // wq/wk/wv (L,H,D,64): per-(l,h) transpose [D,64]->[64,D] into qkvw rows {q|k|v}
  k_transpose_bf16<<<dim3(2, 32, L_*H_), tb, 0, stream>>>(
      wq, qkvw + 0 * 1024 * 1024, D_, 64,
      (long)H_*D_*64, (long)D_*64, (long)3*1024*1024, (long)64*1024, H_);
  k_transpose_bf16<<<dim3(2, 32, L_*H_), tb, 0, stream>>>(
      wk, qkvw + 1 * 1024 * 1024, D_, 64,
      (long)H_*D_*64, (long)D_*64, (long)3*1024*1024, (long)64*1024, H_);
  k_transpose_bf16<<<dim3(2, 32, L_*H_), tb, 0, stream>>>(
      wv, qkvw + 2 * 1024 * 1024, D_, 64,
      (long)H_*D_*64, (long)D_*64, (long)3*1024*1024, (long)64*1024, H_);
  k_transpose_bf16<<<dim3(32, 32, L_), tb, 0, stream>>>(
      wo, wot, 1024, 1024, (long)1024*1024, 0, (long)1024*1024, 0, 1);
  k_transpose_bf16<<<dim3(128, 32, L_), tb, 0, stream>>>(
      w1, w1t, 1024, 4096, (long)1024*4096, 0, (long)1024*4096, 0, 1);
  k_transpose_bf16<<<dim3(32, 128, L_), tb, 0, stream>>>(
      w2, w2t, 4096, 1024, (long)4096*1024, 0, (long)4096*1024, 0, 1);
  k_transpose_bf16<<<dim3(1000, 32, 1), tb, 0, stream>>>(
      lmw, lmwt, 1024, V_, 0, 0, 0, 0, 1);

  k_embed<<<M_, 256, 0, stream>>>(idx, tok, pos, x);

  for (int l = 0; l < L_; ++l) {
    k_ln<<<M_, 256, 0, stream>>>(x, ln1g + l * D_, ln1b + l * D_, hbuf);
    // QKV: [4096,1024] x [3072,1024]^T -> qkv f32
    k_gemm<false, false, false, false><<<dim3(24, 32), 256, 0, stream>>>(
        hbuf, qkvw + (size_t)l * 3072 * 1024, qkv, nullptr, nullptr, nullptr, 3072, 1024);
    k_attn<<<dim3(S_ / 64, B_ * H_), 256, 0, stream>>>(qkv, attb);
    // out-proj + residual -> x
    k_gemm<false, false, true, false><<<dim3(8, 32), 256, 0, stream>>>(
        attb, wot + (size_t)l * 1024 * 1024, x, nullptr, nullptr, x, 1024, 1024);
    k_ln<<<M_, 256, 0, stream>>>(x, ln2g + l * D_, ln2b + l * D_, hbuf);
    // FFN1 + bias + relu -> bf16
    k_gemm<true, true, false, true><<<dim3(32, 32), 256, 0, stream>>>(
        hbuf, w1t + (size_t)l * 4096 * 1024, nullptr, ffnb, b1 + l * DFF_, nullptr, 4096, 1024);
    // FFN2 + bias(b2) + residual -> x
    k_gemm<true, false, true, false><<<dim3(8, 32), 256, 0, stream>>>(
        ffnb, w2t + (size_t)l * 1024 * 4096, x, nullptr, b2 + l * D_, x, 1024, 4096);
  }

  k_ln<<<M_, 256, 0, stream>>>(x, lnfg, lnfb, hbuf);
  // LM head: [4096,1024] x [32000,1024]^T + lm_b -> logits f32
  k_gemm<true, false, false, false><<<dim3(V_ / 128, 32), 256, 0, stream>>>(
      hbuf, lmwt, out, nullptr, lmb, nullptr, V_, 1024);
}

// Round 2
// 2148.645 us; speedup vs baseline: 1.5893x; 1.5893x over previous
//
#include <hip/hip_runtime.h>
#include <hip/hip_bf16.h>

// GPT forward: V=32000 D=1024 S=1024 L=4 H=16 DK=DV=64 B=4 DFF=4096
#define V_   32000
#define D_   1024
#define S_   1024
#define L_   4
#define H_   16
#define B_   4
#define DFF_ 4096
#define M_   (B_*S_)   // 4096 token rows

using bf_t = __hip_bfloat16;
typedef __bf16 bf16x8 __attribute__((ext_vector_type(8)));
typedef float  f32x4  __attribute__((ext_vector_type(4)));

#define AS1(p) ((__attribute__((address_space(1))) void*)(p))
#define AS3(p) ((__attribute__((address_space(3))) void*)(p))

// ---------------------------------------------------------------------------
// Transpose f32 [R,C] -> bf16 [C,R], batched over two strides (z = z1*n2+z2)
// ---------------------------------------------------------------------------
__global__ __launch_bounds__(256) void k_transpose_bf16(
    const float* __restrict__ src, bf_t* __restrict__ dst,
    int R, int C, long srcS1, long srcS2, long dstS1, long dstS2, int n2)
{
  const int z  = blockIdx.z;
  const int z1 = z / n2, z2 = z % n2;
  src += (size_t)z1 * srcS1 + (size_t)z2 * srcS2;
  dst += (size_t)z1 * dstS1 + (size_t)z2 * dstS2;
  __shared__ float tile[32][33];
  const int c0 = blockIdx.x * 32, r0 = blockIdx.y * 32;
  const int lx = threadIdx.x, ly = threadIdx.y;  // 32 x 8
  #pragma unroll
  for (int i = 0; i < 32; i += 8)
    tile[ly + i][lx] = src[(size_t)(r0 + ly + i) * C + (c0 + lx)];
  __syncthreads();
  #pragma unroll
  for (int i = 0; i < 32; i += 8)
    dst[(size_t)(c0 + ly + i) * R + (r0 + lx)] = __float2bfloat16(tile[lx][ly + i]);
}

// ---------------------------------------------------------------------------
// Embedding: x[b,s,:] = tok_emb[idx[b,s],:] + pos_emb[s,:]
// ---------------------------------------------------------------------------
__global__ __launch_bounds__(256) void k_embed(
    const int* __restrict__ idx, const float* __restrict__ tok,
    const float* __restrict__ pos, float* __restrict__ x)
{
  const int row = blockIdx.x;          // b*S + s
  const int s   = row & (S_ - 1);
  const int t   = idx[row];
  const float4* tr = (const float4*)(tok + (size_t)t * D_);
  const float4* pr = (const float4*)(pos + (size_t)s * D_);
  float4* xr = (float4*)(x + (size_t)row * D_);
  const int i = threadIdx.x;           // 256 threads * float4 = 1024 floats
  float4 a = tr[i], b = pr[i];
  xr[i] = make_float4(a.x + b.x, a.y + b.y, a.z + b.z, a.w + b.w);
}

// ---------------------------------------------------------------------------
// LayerNorm (f32 in) -> bf16 out.  One block (256 thr) per row, D=1024.
// ---------------------------------------------------------------------------
__global__ __launch_bounds__(256) void k_ln(
    const float* __restrict__ x, const float* __restrict__ g,
    const float* __restrict__ bb, bf_t* __restrict__ out)
{
  __shared__ float red[8];
  const int row = blockIdx.x, tid = threadIdx.x;
  const float4 v = ((const float4*)(x + (size_t)row * D_))[tid];
  float s = v.x + v.y + v.z + v.w;
  #pragma unroll
  for (int o = 32; o > 0; o >>= 1) s += __shfl_down(s, o);
  if ((tid & 63) == 0) red[tid >> 6] = s;
  __syncthreads();
  const float mu = (red[0] + red[1] + red[2] + red[3]) * (1.f / D_);
  const float dx = v.x - mu, dy = v.y - mu, dz = v.z - mu, dw = v.w - mu;
  float ss = dx*dx + dy*dy + dz*dz + dw*dw;
  #pragma unroll
  for (int o = 32; o > 0; o >>= 1) ss += __shfl_down(ss, o);
  if ((tid & 63) == 0) red[4 + (tid >> 6)] = ss;
  __syncthreads();
  const float var = (red[4] + red[5] + red[6] + red[7]) * (1.f / D_);
  const float rs  = rsqrtf(var + 1e-5f);
  const float4 gv = ((const float4*)g)[tid];
  const float4 bv = ((const float4*)bb)[tid];
  const size_t base = (size_t)row * D_ + tid * 4;
  out[base + 0] = __float2bfloat16(dx * rs * gv.x + bv.x);
  out[base + 1] = __float2bfloat16(dy * rs * gv.y + bv.y);
  out[base + 2] = __float2bfloat16(dz * rs * gv.z + bv.z);
  out[base + 3] = __float2bfloat16(dw * rs * gv.w + bv.w);
}

// ---------------------------------------------------------------------------
// bf16 MFMA GEMM: C[M,N] = A[M,K] * Bt[N,K]^T  (+bias +residual, relu, out f32/bf16)
// m97 structure: 128x128 tile, BK=64, 4 waves (2x2 of 64x64), 16x16x32 MFMA,
// global_load_lds width=16, linear LDS, 2 barriers per K-step.
// 1D grid = (N/128)*(M/128); XCD-swizzled, m-inner tile order (B-panel L2 reuse).
// M is always 4096 here -> 32 m-tiles hardcoded.
// ---------------------------------------------------------------------------
template<bool HAS_BIAS, bool RELU, bool RESID, bool OUT_BF16>
__global__ __launch_bounds__(256) void k_gemm(
    const bf_t* __restrict__ A, const bf_t* __restrict__ Bt,
    float* outF, bf_t* outB,
    const float* __restrict__ bias, const float* resid,
    int N, int K)
{
  __shared__ __bf16 As[128 * 64];
  __shared__ __bf16 Bs[128 * 64];
  const int tid  = threadIdx.x;
  const int lane = tid & 63, wid = tid >> 6;
  // XCD-aware bijective swizzle (gridDim.x % 8 == 0 for all launches),
  // then m-inner decompose: consecutive tiles share the B panel.
  const int cpx = gridDim.x >> 3;
  const int swz = (blockIdx.x & 7) * cpx + (blockIdx.x >> 3);
  const int m0 = (swz & 31) * 128;
  const int n0 = (swz >> 5) * 128;
  f32x4 acc[4][4] = {};

  const int srow = lane >> 3;        // 0..7 within 8-row chunk
  const int scol = (lane & 7) * 8;   // k-element offset (16B)
  const int mw = (wid >> 1) * 64, nw = (wid & 1) * 64;

  for (int kt = 0; kt < K; kt += 64) {
    #pragma unroll
    for (int i = 0; i < 4; ++i) {
      const int chunk = i * 4 + wid;           // wave-uniform
      const int r = chunk * 8 + srow;
      const bf_t* sa = A  + (size_t)(m0 + r) * K + kt + scol;
      const bf_t* sb = Bt + (size_t)(n0 + r) * K + kt + scol;
      __builtin_amdgcn_global_load_lds(AS1(sa), AS3(&As[chunk * 512]), 16, 0, 0);
      __builtin_amdgcn_global_load_lds(AS1(sb), AS3(&Bs[chunk * 512]), 16, 0, 0);
    }
    asm volatile("s_waitcnt vmcnt(0)" ::: "memory");
    __syncthreads();
    #pragma unroll
    for (int kk = 0; kk < 2; ++kk) {
      bf16x8 af[4], bfr[4];
      #pragma unroll
      for (int mi = 0; mi < 4; ++mi)
        af[mi] = *(const bf16x8*)&As[(mw + mi * 16 + (lane & 15)) * 64 + kk * 32 + (lane >> 4) * 8];
      #pragma unroll
      for (int ni = 0; ni < 4; ++ni)
        bfr[ni] = *(const bf16x8*)&Bs[(nw + ni * 16 + (lane & 15)) * 64 + kk * 32 + (lane >> 4) * 8];
      #pragma unroll
      for (int mi = 0; mi < 4; ++mi)
        #pragma unroll
        for (int ni = 0; ni < 4; ++ni)
          acc[mi][ni] = __builtin_amdgcn_mfma_f32_16x16x32_bf16(af[mi], bfr[ni], acc[mi][ni], 0, 0, 0);
    }
    __syncthreads();
  }

  // epilogue — C/D layout: col = lane&15, row = (lane>>4)*4 + j  [verified]
  const int cr = (lane >> 4) * 4, cc = lane & 15;
  #pragma unroll
  for (int mi = 0; mi < 4; ++mi) {
    #pragma unroll
    for (int ni = 0; ni < 4; ++ni) {
      const int col = n0 + nw + ni * 16 + cc;
      const float bv = HAS_BIAS ? bias[col] : 0.f;
      #pragma unroll
      for (int j = 0; j < 4; ++j) {
        const int row = m0 + mw + mi * 16 + cr + j;
        float v = acc[mi][ni][j] + bv;
        if (RESID) v += resid[(size_t)row * N + col];
        if (RELU)  v = fmaxf(v, 0.f);
        if (OUT_BF16) outB[(size_t)row * N + col] = __float2bfloat16(v);
        else          outF[(size_t)row * N + col] = v;
      }
    }
  }
}

// ---------------------------------------------------------------------------
// MFMA flash attention (bf16 in, f32 online softmax, bf16 out).
// qkv layout: bf16 [B*S][3072] = Q|K|V, 64 per head.  Grid (S/64, B*H), 256 thr.
// Per block: 64 q-rows of one (b,h).  4 waves, each owns 16 q-rows x all 64 cols.
// LDS tiles 64x64 bf16, XOR-chunk-swizzled (T2) so all ds_read_b128 column-slice
// reads and the V-transpose scatter writes are <=2-way (free, m136).
//   Qs/Ks/Ps: elem(r,c) at r*64 + ((c>>3)^(r&7))*8 + (c&7)
//   Vt      : elem(d,t) at d*64 + (((t>>3)^(d&7)^((d>>3)&7))*8) + (t&7)
// ---------------------------------------------------------------------------
__global__ __launch_bounds__(256) void k_attn_mfma(
    const bf_t* __restrict__ qkv, bf_t* __restrict__ o)
{
  __shared__ __bf16 Qs[64 * 64];
  __shared__ __bf16 Ks[64 * 64];
  __shared__ __bf16 Vt[64 * 64];
  __shared__ __bf16 Ps[4][16 * 64];   // wave-private P tiles

  const int qt = blockIdx.x, bh = blockIdx.y;
  const int b = bh >> 4, h = bh & 15;
  const int tid = threadIdx.x, lane = tid & 63, wid = tid >> 6;
  const int qbase = qt * 64;
  const int r0 = wid * 16;            // this wave's q-row base within tile
  const int l4 = lane & 15, lhi = lane >> 4;

  // stage Q once (512 chunks of 8 bf16; 2 passes x 256 threads)
  #pragma unroll
  for (int p = 0; p < 2; ++p) {
    const int idx = p * 256 + tid;
    const int r = idx >> 3, c8 = idx & 7;
    const bf16x8 v = *(const bf16x8*)(qkv + (size_t)(b * S_ + qbase + r) * 3072 + h * 64 + c8 * 8);
    *(bf16x8*)&Qs[r * 64 + ((c8 ^ (r & 7)) * 8)] = v;
  }

  f32x4 oa[4];
  #pragma unroll
  for (int di = 0; di < 4; ++di) oa[di] = (f32x4){0.f, 0.f, 0.f, 0.f};
  float mrow[4] = {-1e30f, -1e30f, -1e30f, -1e30f};
  float lrow[4] = {0.f, 0.f, 0.f, 0.f};

  const float SCL = 0.125f * 1.44269504089f;  // 1/sqrt(DK) * log2(e): log2-domain softmax

  for (int kt = 0; kt <= qt; ++kt) {
    __syncthreads();                  // all waves done reading Ks/Vt of prev iter
    #pragma unroll
    for (int p = 0; p < 2; ++p) {
      const int idx = p * 256 + tid;
      const int r = idx >> 3, c8 = idx & 7;
      const size_t gbase = (size_t)(b * S_ + kt * 64 + r) * 3072 + h * 64 + c8 * 8;
      const bf16x8 kv = *(const bf16x8*)(qkv + gbase + 1024);
      *(bf16x8*)&Ks[r * 64 + ((c8 ^ (r & 7)) * 8)] = kv;
      const bf16x8 vv = *(const bf16x8*)(qkv + gbase + 2048);
      #pragma unroll
      for (int i = 0; i < 8; ++i) {   // transpose-scatter: d = c8*8+i -> d&7=i, d>>3=c8
        const int d = c8 * 8 + i;
        Vt[d * 64 + (((r >> 3) ^ i ^ c8) * 8) + (r & 7)] = vv[i];
      }
    }
    __syncthreads();

    // --- QK^T: wave rows r0..r0+15  x  cols 0..63 ---
    f32x4 s[4];
    #pragma unroll
    for (int ni = 0; ni < 4; ++ni) s[ni] = (f32x4){0.f, 0.f, 0.f, 0.f};
    const int qr = r0 + l4;
    __builtin_amdgcn_s_setprio(1);
    #pragma unroll
    for (int kk = 0; kk < 2; ++kk) {
      const int ck = kk * 4 + lhi;    // 16B chunk index along K
      const bf16x8 aq = *(const bf16x8*)&Qs[qr * 64 + ((ck ^ (qr & 7)) * 8)];
      #pragma unroll
      for (int ni = 0; ni < 4; ++ni) {
        const int t = ni * 16 + l4;
        const bf16x8 bk = *(const bf16x8*)&Ks[t * 64 + ((ck ^ (t & 7)) * 8)];
        s[ni] = __builtin_amdgcn_mfma_f32_16x16x32_bf16(aq, bk, s[ni], 0, 0, 0);
      }
    }
    __builtin_amdgcn_s_setprio(0);

    // scale into log2 domain; mask only the diagonal tile
    #pragma unroll
    for (int ni = 0; ni < 4; ++ni)
      #pragma unroll
      for (int j = 0; j < 4; ++j)
        s[ni][j] *= SCL;
    if (kt == qt) {
      #pragma unroll
      for (int ni = 0; ni < 4; ++ni) {
        const int t = ni * 16 + l4;
        #pragma unroll
        for (int j = 0; j < 4; ++j)
          if (t > r0 + lhi * 4 + j) s[ni][j] = -1e30f;
      }
    }

    // --- online softmax: row r = (lhi*4+j), values spread over 16 lanes x 4 ni ---
    #pragma unroll
    for (int j = 0; j < 4; ++j) {
      float m_ = fmaxf(fmaxf(s[0][j], s[1][j]), fmaxf(s[2][j], s[3][j]));
      m_ = fmaxf(m_, __shfl_xor(m_, 1));
      m_ = fmaxf(m_, __shfl_xor(m_, 2));
      m_ = fmaxf(m_, __shfl_xor(m_, 4));
      m_ = fmaxf(m_, __shfl_xor(m_, 8));
      const float mnew = fmaxf(mrow[j], m_);
      const float c = exp2f(mrow[j] - mnew);
      mrow[j] = mnew;
      float ssum = 0.f;
      #pragma unroll
      for (int ni = 0; ni < 4; ++ni) {
        const float pv = exp2f(s[ni][j] - mnew);
        s[ni][j] = pv;
        ssum += pv;
      }
      ssum += __shfl_xor(ssum, 1);
      ssum += __shfl_xor(ssum, 2);
      ssum += __shfl_xor(ssum, 4);
      ssum += __shfl_xor(ssum, 8);
      lrow[j] = lrow[j] * c + ssum;
      #pragma unroll
      for (int di = 0; di < 4; ++di) oa[di][j] *= c;
    }

    // --- P -> wave-private LDS (bf16), swizzled like Qs ---
    #pragma unroll
    for (int ni = 0; ni < 4; ++ni)
      #pragma unroll
      for (int j = 0; j < 4; ++j) {
        const int r = lhi * 4 + j;
        const int c = ni * 16 + l4;
        Ps[wid][r * 64 + (((c >> 3) ^ (r & 7)) * 8) + (c & 7)] = (__bf16)s[ni][j];
      }

    // --- PV: O(16x64) += P(16x64) * V(64x64), B-operand = Vt rows (d) ---
    __builtin_amdgcn_s_setprio(1);
    #pragma unroll
    for (int kk = 0; kk < 2; ++kk) {
      const int ck = kk * 4 + lhi;    // chunk along t
      const bf16x8 ap = *(const bf16x8*)&Ps[wid][l4 * 64 + ((ck ^ (l4 & 7)) * 8)];
      #pragma unroll
      for (int di = 0; di < 4; ++di) {
        const int d = di * 16 + l4;
        const bf16x8 bv = *(const bf16x8*)&Vt[d * 64 + ((ck ^ (d & 7) ^ ((d >> 3) & 7)) * 8)];
        oa[di] = __builtin_amdgcn_mfma_f32_16x16x32_bf16(ap, bv, oa[di], 0, 0, 0);
      }
    }
    __builtin_amdgcn_s_setprio(0);
  }

  // epilogue: normalize and store bf16
  #pragma unroll
  for (int j = 0; j < 4; ++j) {
    const float inv = 1.f / lrow[j];
    const size_t row = (size_t)(b * S_) + qbase + r0 + lhi * 4 + j;
    #pragma unroll
    for (int di = 0; di < 4; ++di)
      o[row * 1024 + h * 64 + di * 16 + l4] = __float2bfloat16(oa[di][j] * inv);
  }
}

// ---------------------------------------------------------------------------
extern "C" void kernel_launch(void* const* d_in, const int* in_sizes, int n_in,
                              void* d_out, int out_size, void* d_ws, size_t ws_size,
                              hipStream_t stream)
{
  (void)in_sizes; (void)n_in; (void)out_size; (void)ws_size;
  const int*   idx  = (const int*)  d_in[0];
  const float* tok  = (const float*)d_in[1];
  const float* pos  = (const float*)d_in[2];
  const float* wq   = (const float*)d_in[3];
  const float* wk   = (const float*)d_in[4];
  const float* wv   = (const float*)d_in[5];
  const float* wo   = (const float*)d_in[6];
  const float* w1   = (const float*)d_in[7];
  const float* b1   = (const float*)d_in[8];
  const float* w2   = (const float*)d_in[9];
  const float* b2   = (const float*)d_in[10];
  const float* ln1g = (const float*)d_in[11];
  const float* ln1b = (const float*)d_in[12];
  const float* ln2g = (const float*)d_in[13];
  const float* ln2b = (const float*)d_in[14];
  const float* lnfg = (const float*)d_in[15];
  const float* lnfb = (const float*)d_in[16];
  const float* lmw  = (const float*)d_in[17];
  const float* lmb  = (const float*)d_in[18];
  float* out = (float*)d_out;

  // workspace carve-up (~258 MB)
  char* ws = (char*)d_ws;
  size_t off = 0;
  auto alloc = [&](size_t bytes) {
    void* p = ws + off; off += (bytes + 255) & ~(size_t)255; return p;
  };
  bf_t*  qkvw = (bf_t*) alloc((size_t)L_ * 3072 * 1024 * 2);  // Bt [3072][1024] per layer
  bf_t*  wot  = (bf_t*) alloc((size_t)L_ * 1024 * 1024 * 2);  // Bt [1024][1024]
  bf_t*  w1t  = (bf_t*) alloc((size_t)L_ * 4096 * 1024 * 2);  // Bt [4096][1024]
  bf_t*  w2t  = (bf_t*) alloc((size_t)L_ * 1024 * 4096 * 2);  // Bt [1024][4096]
  bf_t*  lmwt = (bf_t*) alloc((size_t)V_ * 1024 * 2);         // Bt [32000][1024]
  float* x    = (float*)alloc((size_t)M_ * D_ * 4);
  bf_t*  hbuf = (bf_t*) alloc((size_t)M_ * D_ * 2);
  bf_t*  qkvb = (bf_t*) alloc((size_t)M_ * 3072 * 2);         // bf16 QKV activations
  bf_t*  attb = (bf_t*) alloc((size_t)M_ * D_ * 2);
  bf_t*  ffnb = (bf_t*) alloc((size_t)M_ * DFF_ * 2);

  const dim3 tb(32, 8);
  // wq/wk/wv (L,H,D,64): per-(l,h) transpose [D,64]->[64,D] into qkvw rows {q|k|v}
  k_transpose_bf16<<<dim3(2, 32, L_*H_), tb, 0, stream>>>(
      wq, qkvw + 0 * 1024 * 1024, D_, 64,
      (long)H_*D_*64, (long)D_*64, (long)3*1024*1024, (long)64*1024, H_);
  k_transpose_bf16<<<dim3(2, 32, L_*H_), tb, 0, stream>>>(
      wk, qkvw + 1 * 1024 * 1024, D_, 64,
      (long)H_*D_*64, (long)D_*64, (long)3*1024*1024, (long)64*1024, H_);
  k_transpose_bf16<<<dim3(2, 32, L_*H_), tb, 0, stream>>>(
      wv, qkvw + 2 * 1024 * 1024, D_, 64,
      (long)H_*D_*64, (long)D_*64, (long)3*1024*1024, (long)64*1024, H_);
  k_transpose_bf16<<<dim3(32, 32, L_), tb, 0, stream>>>(
      wo, wot, 1024, 1024, (long)1024*1024, 0, (long)1024*1024, 0, 1);
  k_transpose_bf16<<<dim3(128, 32, L_), tb, 0, stream>>>(
      w1, w1t, 1024, 4096, (long)1024*4096, 0, (long)1024*4096, 0, 1);
  k_transpose_bf16<<<dim3(32, 128, L_), tb, 0, stream>>>(
      w2, w2t, 4096, 1024, (long)4096*1024, 0, (long)4096*1024, 0, 1);
  k_transpose_bf16<<<dim3(1000, 32, 1), tb, 0, stream>>>(
      lmw, lmwt, 1024, V_, 0, 0, 0, 0, 1);

  k_embed<<<M_, 256, 0, stream>>>(idx, tok, pos, x);

  for (int l = 0; l < L_; ++l) {
    k_ln<<<M_, 256, 0, stream>>>(x, ln1g + l * D_, ln1b + l * D_, hbuf);
    // QKV: [4096,1024] x [3072,1024]^T -> bf16
    k_gemm<false, false, false, true><<<24 * 32, 256, 0, stream>>>(
        hbuf, qkvw + (size_t)l * 3072 * 1024, nullptr, qkvb, nullptr, nullptr, 3072, 1024);
    k_attn_mfma<<<dim3(S_ / 64, B_ * H_), 256, 0, stream>>>(qkvb, attb);
    // out-proj + residual -> x
    k_gemm<false, false, true, false><<<8 * 32, 256, 0, stream>>>(
        attb, wot + (size_t)l * 1024 * 1024, x, nullptr, nullptr, x, 1024, 1024);
    k_ln<<<M_, 256, 0, stream>>>(x, ln2g + l * D_, ln2b + l * D_, hbuf);
    // FFN1 + bias + relu -> bf16
    k_gemm<true, true, false, true><<<32 * 32, 256, 0, stream>>>(
        hbuf, w1t + (size_t)l * 4096 * 1024, nullptr, ffnb, b1 + l * DFF_, nullptr, 4096, 1024);
    // FFN2 + bias(b2) + residual -> x
    k_gemm<true, false, true, false><<<8 * 32, 256, 0, stream>>>(
        ffnb, w2t + (size_t)l * 1024 * 4096, x, nullptr, b2 + l * D_, x, 1024, 4096);
  }

  k_ln<<<M_, 256, 0, stream>>>(x, lnfg, lnfb, hbuf);
  // LM head: [4096,1024] x [32000,1024]^T + lm_b -> logits f32
  k_gemm<true, false, false, false><<<(V_ / 128) * 32, 256, 0, stream>>>(
      hbuf, lmwt, out, nullptr, lmb, nullptr, V_, 1024);
}

// Round 3
// 1729.276 us; speedup vs baseline: 1.9748x; 1.2425x over previous
//
#include <hip/hip_runtime.h>
#include <hip/hip_bf16.h>

// GPT forward: V=32000 D=1024 S=1024 L=4 H=16 DK=DV=64 B=4 DFF=4096
#define V_   32000
#define D_   1024
#define S_   1024
#define L_   4
#define H_   16
#define B_   4
#define DFF_ 4096
#define M_   (B_*S_)   // 4096 token rows

using bf_t = __hip_bfloat16;
typedef __bf16 bf16x8 __attribute__((ext_vector_type(8)));
typedef float  f32x4  __attribute__((ext_vector_type(4)));

#define AS1(p) ((__attribute__((address_space(1))) void*)(p))
#define AS3(p) ((__attribute__((address_space(3))) void*)(p))

// ---------------------------------------------------------------------------
// Transpose f32 [R,C] -> bf16 [C,R], batched over two strides (z = z1*n2+z2)
// ---------------------------------------------------------------------------
__global__ __launch_bounds__(256) void k_transpose_bf16(
    const float* __restrict__ src, bf_t* __restrict__ dst,
    int R, int C, long srcS1, long srcS2, long dstS1, long dstS2, int n2)
{
  const int z  = blockIdx.z;
  const int z1 = z / n2, z2 = z % n2;
  src += (size_t)z1 * srcS1 + (size_t)z2 * srcS2;
  dst += (size_t)z1 * dstS1 + (size_t)z2 * dstS2;
  __shared__ float tile[32][33];
  const int c0 = blockIdx.x * 32, r0 = blockIdx.y * 32;
  const int lx = threadIdx.x, ly = threadIdx.y;  // 32 x 8
  #pragma unroll
  for (int i = 0; i < 32; i += 8)
    tile[ly + i][lx] = src[(size_t)(r0 + ly + i) * C + (c0 + lx)];
  __syncthreads();
  #pragma unroll
  for (int i = 0; i < 32; i += 8)
    dst[(size_t)(c0 + ly + i) * R + (r0 + lx)] = __float2bfloat16(tile[lx][ly + i]);
}

// ---------------------------------------------------------------------------
// Embedding: x[b,s,:] = tok_emb[idx[b,s],:] + pos_emb[s,:]
// ---------------------------------------------------------------------------
__global__ __launch_bounds__(256) void k_embed(
    const int* __restrict__ idx, const float* __restrict__ tok,
    const float* __restrict__ pos, float* __restrict__ x)
{
  const int row = blockIdx.x;          // b*S + s
  const int s   = row & (S_ - 1);
  const int t   = idx[row];
  const float4* tr = (const float4*)(tok + (size_t)t * D_);
  const float4* pr = (const float4*)(pos + (size_t)s * D_);
  float4* xr = (float4*)(x + (size_t)row * D_);
  const int i = threadIdx.x;           // 256 threads * float4 = 1024 floats
  float4 a = tr[i], b = pr[i];
  xr[i] = make_float4(a.x + b.x, a.y + b.y, a.z + b.z, a.w + b.w);
}

// ---------------------------------------------------------------------------
// LayerNorm (f32 in) -> bf16 out.  One block (256 thr) per row, D=1024.
// ---------------------------------------------------------------------------
__global__ __launch_bounds__(256) void k_ln(
    const float* __restrict__ x, const float* __restrict__ g,
    const float* __restrict__ bb, bf_t* __restrict__ out)
{
  __shared__ float red[8];
  const int row = blockIdx.x, tid = threadIdx.x;
  const float4 v = ((const float4*)(x + (size_t)row * D_))[tid];
  float s = v.x + v.y + v.z + v.w;
  #pragma unroll
  for (int o = 32; o > 0; o >>= 1) s += __shfl_down(s, o);
  if ((tid & 63) == 0) red[tid >> 6] = s;
  __syncthreads();
  const float mu = (red[0] + red[1] + red[2] + red[3]) * (1.f / D_);
  const float dx = v.x - mu, dy = v.y - mu, dz = v.z - mu, dw = v.w - mu;
  float ss = dx*dx + dy*dy + dz*dz + dw*dw;
  #pragma unroll
  for (int o = 32; o > 0; o >>= 1) ss += __shfl_down(ss, o);
  if ((tid & 63) == 0) red[4 + (tid >> 6)] = ss;
  __syncthreads();
  const float var = (red[4] + red[5] + red[6] + red[7]) * (1.f / D_);
  const float rs  = rsqrtf(var + 1e-5f);
  const float4 gv = ((const float4*)g)[tid];
  const float4 bv = ((const float4*)bb)[tid];
  const size_t base = (size_t)row * D_ + tid * 4;
  out[base + 0] = __float2bfloat16(dx * rs * gv.x + bv.x);
  out[base + 1] = __float2bfloat16(dy * rs * gv.y + bv.y);
  out[base + 2] = __float2bfloat16(dz * rs * gv.z + bv.z);
  out[base + 3] = __float2bfloat16(dw * rs * gv.w + bv.w);
}

// ---------------------------------------------------------------------------
// Combine pass for split-K GEMMs: x += sum_p P[p] (+ bias per column).
// Grid M_ blocks x 256 thr; one row per block (1024 f32 = 256 float4).
// ---------------------------------------------------------------------------
__global__ __launch_bounds__(256) void k_combine(
    float* __restrict__ x, const float* __restrict__ P,
    const float* __restrict__ bias, int nparts, long pstride)
{
  const size_t i = (size_t)blockIdx.x * 256 + threadIdx.x;  // float4 index
  float4 a = ((float4*)x)[i];
  for (int p = 0; p < nparts; ++p) {
    const float4 v = ((const float4*)(P + (size_t)p * pstride))[i];
    a.x += v.x; a.y += v.y; a.z += v.z; a.w += v.w;
  }
  if (bias) {
    const float4 bv = ((const float4*)bias)[threadIdx.x];
    a.x += bv.x; a.y += bv.y; a.z += bv.z; a.w += bv.w;
  }
  ((float4*)x)[i] = a;
}

// ---------------------------------------------------------------------------
// bf16 MFMA GEMM: C[M,N] = A[M,K] * Bt[N,K]^T  (+bias, relu, out f32/bf16,
// optional nontemporal f32 stores, optional split-K into PARTS partials).
// m97 structure: 128x128 tile, BK=64, 4 waves (2x2 of 64x64), 16x16x32 MFMA,
// global_load_lds width=16, linear LDS, 2 barriers per K-step.
// 1D grid = PARTS*(M/128)*nN, XCD-swizzled; n-fast tile order within chunk
// (consecutive tiles share the A panel -> L2-hot; B streams via L3).
// ---------------------------------------------------------------------------
template<bool HAS_BIAS, bool RELU, bool OUT_BF16, bool NT, int PARTS>
__global__ __launch_bounds__(256) void k_gemm(
    const bf_t* __restrict__ A, const bf_t* __restrict__ Bt,
    float* outF, bf_t* outB,
    const float* __restrict__ bias,
    int N, int nN, int ld, int Klen, long pstride)
{
  __shared__ __bf16 As[128 * 64];
  __shared__ __bf16 Bs[128 * 64];
  const int tid  = threadIdx.x;
  const int lane = tid & 63, wid = tid >> 6;
  // bijective XCD swizzle (gridDim.x % 8 == 0 always here)
  const int cpx = gridDim.x >> 3;
  const int swz = (blockIdx.x & 7) * cpx + (blockIdx.x >> 3);
  int tile = swz, kh = 0;
  if (PARTS > 1) { const int T = gridDim.x / PARTS; kh = swz / T; tile = swz % T; }
  const int m0 = (tile / nN) * 128;
  const int n0 = (tile % nN) * 128;
  const int kb = kh * Klen;
  f32x4 acc[4][4] = {};

  const int srow = lane >> 3;        // 0..7 within 8-row chunk
  const int scol = (lane & 7) * 8;   // k-element offset (16B)
  const int mw = (wid >> 1) * 64, nw = (wid & 1) * 64;

  for (int kt = 0; kt < Klen; kt += 64) {
    #pragma unroll
    for (int i = 0; i < 4; ++i) {
      const int chunk = i * 4 + wid;           // wave-uniform
      const int r = chunk * 8 + srow;
      const bf_t* sa = A  + (size_t)(m0 + r) * ld + kb + kt + scol;
      const bf_t* sb = Bt + (size_t)(n0 + r) * ld + kb + kt + scol;
      __builtin_amdgcn_global_load_lds(AS1(sa), AS3(&As[chunk * 512]), 16, 0, 0);
      __builtin_amdgcn_global_load_lds(AS1(sb), AS3(&Bs[chunk * 512]), 16, 0, 0);
    }
    asm volatile("s_waitcnt vmcnt(0)" ::: "memory");
    __syncthreads();
    #pragma unroll
    for (int kk = 0; kk < 2; ++kk) {
      bf16x8 af[4], bfr[4];
      #pragma unroll
      for (int mi = 0; mi < 4; ++mi)
        af[mi] = *(const bf16x8*)&As[(mw + mi * 16 + (lane & 15)) * 64 + kk * 32 + (lane >> 4) * 8];
      #pragma unroll
      for (int ni = 0; ni < 4; ++ni)
        bfr[ni] = *(const bf16x8*)&Bs[(nw + ni * 16 + (lane & 15)) * 64 + kk * 32 + (lane >> 4) * 8];
      #pragma unroll
      for (int mi = 0; mi < 4; ++mi)
        #pragma unroll
        for (int ni = 0; ni < 4; ++ni)
          acc[mi][ni] = __builtin_amdgcn_mfma_f32_16x16x32_bf16(af[mi], bfr[ni], acc[mi][ni], 0, 0, 0);
    }
    __syncthreads();
  }

  // epilogue — C/D layout: col = lane&15, row = (lane>>4)*4 + j  [verified]
  float* outP = outF + (PARTS > 1 ? (size_t)kh * pstride : 0);
  const int cr = (lane >> 4) * 4, cc = lane & 15;
  #pragma unroll
  for (int mi = 0; mi < 4; ++mi) {
    #pragma unroll
    for (int ni = 0; ni < 4; ++ni) {
      const int col = n0 + nw + ni * 16 + cc;
      const float bv = HAS_BIAS ? bias[col] : 0.f;
      #pragma unroll
      for (int j = 0; j < 4; ++j) {
        const int row = m0 + mw + mi * 16 + cr + j;
        float v = acc[mi][ni][j] + bv;
        if (RELU)  v = fmaxf(v, 0.f);
        if (OUT_BF16) {
          outB[(size_t)row * N + col] = __float2bfloat16(v);
        } else if (NT) {
          __builtin_nontemporal_store(v, &outP[(size_t)row * N + col]);
        } else {
          outP[(size_t)row * N + col] = v;
        }
      }
    }
  }
}

// ---------------------------------------------------------------------------
// MFMA flash attention (bf16 in, f32 online softmax, bf16 out).
// qkv layout: bf16 [B*S][3072] = Q|K|V, 64 per head.  Grid (S/64, B*H), 256 thr.
// Per block: 64 q-rows of one (b,h).  4 waves, each owns 16 q-rows.
// SWAPPED QK^T: s = mfma(K, Q) so scores land [t][q] with q = lane&15 ->
// softmax row-reduce is register-local + 2 shfl_xor (vs 32 shfls).
// T13 defer-max (THR=8, log2 domain) skips O-rescale on stable tiles.
// LDS tiles 64x64 bf16, XOR-chunk-swizzled (T2): all ds_read_b128 column-slice
// reads and the V-transpose scatter writes are <=2-way (free, m136).
// ---------------------------------------------------------------------------
__global__ __launch_bounds__(256) void k_attn_mfma(
    const bf_t* __restrict__ qkv, bf_t* __restrict__ o)
{
  __shared__ __bf16 Qs[64 * 64];
  __shared__ __bf16 Ks[64 * 64];
  __shared__ __bf16 Vt[64 * 64];
  __shared__ __bf16 Ps[4][16 * 64];   // wave-private P tiles

  const int qt = blockIdx.x, bh = blockIdx.y;
  const int b = bh >> 4, h = bh & 15;
  const int tid = threadIdx.x, lane = tid & 63, wid = tid >> 6;
  const int qbase = qt * 64;
  const int r0 = wid * 16;            // this wave's q-row base within tile
  const int l4 = lane & 15, lhi = lane >> 4;

  // stage Q once (512 chunks of 8 bf16; 2 passes x 256 threads)
  #pragma unroll
  for (int p = 0; p < 2; ++p) {
    const int idx = p * 256 + tid;
    const int r = idx >> 3, c8 = idx & 7;
    const bf16x8 v = *(const bf16x8*)(qkv + (size_t)(b * S_ + qbase + r) * 3072 + h * 64 + c8 * 8);
    *(bf16x8*)&Qs[r * 64 + ((c8 ^ (r & 7)) * 8)] = v;
  }

  f32x4 oa[4];
  #pragma unroll
  for (int di = 0; di < 4; ++di) oa[di] = (f32x4){0.f, 0.f, 0.f, 0.f};
  float mrow = -1e30f, lrow = 0.f;    // state for q = l4 (dup across lhi)

  const float SCL = 0.125f * 1.44269504089f;  // 1/sqrt(DK) * log2(e)

  for (int kt = 0; kt <= qt; ++kt) {
    __syncthreads();                  // all waves done reading Ks/Vt of prev iter
    #pragma unroll
    for (int p = 0; p < 2; ++p) {
      const int idx = p * 256 + tid;
      const int r = idx >> 3, c8 = idx & 7;
      const size_t gbase = (size_t)(b * S_ + kt * 64 + r) * 3072 + h * 64 + c8 * 8;
      const bf16x8 kv = *(const bf16x8*)(qkv + gbase + 1024);
      *(bf16x8*)&Ks[r * 64 + ((c8 ^ (r & 7)) * 8)] = kv;
      const bf16x8 vv = *(const bf16x8*)(qkv + gbase + 2048);
      #pragma unroll
      for (int i = 0; i < 8; ++i) {   // transpose-scatter: d = c8*8+i
        const int d = c8 * 8 + i;
        Vt[d * 64 + (((r >> 3) ^ i ^ c8) * 8) + (r & 7)] = vv[i];
      }
    }
    __syncthreads();

    // --- swapped QK^T: s[ni] holds S^T[t][q], t=ni*16+lhi*4+j, q=r0+l4 ---
    f32x4 s[4];
    #pragma unroll
    for (int ni = 0; ni < 4; ++ni) s[ni] = (f32x4){0.f, 0.f, 0.f, 0.f};
    const int qr = r0 + l4;
    __builtin_amdgcn_s_setprio(1);
    #pragma unroll
    for (int kk = 0; kk < 2; ++kk) {
      const int ck = kk * 4 + lhi;    // 16B chunk index along K(=DK)
      const bf16x8 bq = *(const bf16x8*)&Qs[qr * 64 + ((ck ^ (qr & 7)) * 8)];
      #pragma unroll
      for (int ni = 0; ni < 4; ++ni) {
        const int t = ni * 16 + l4;
        const bf16x8 ak = *(const bf16x8*)&Ks[t * 64 + ((ck ^ (t & 7)) * 8)];
        s[ni] = __builtin_amdgcn_mfma_f32_16x16x32_bf16(ak, bq, s[ni], 0, 0, 0);
      }
    }
    __builtin_amdgcn_s_setprio(0);

    // scale into log2 domain; mask only the diagonal tile
    #pragma unroll
    for (int ni = 0; ni < 4; ++ni)
      #pragma unroll
      for (int j = 0; j < 4; ++j)
        s[ni][j] *= SCL;
    if (kt == qt) {
      #pragma unroll
      for (int ni = 0; ni < 4; ++ni)
        #pragma unroll
        for (int j = 0; j < 4; ++j)
          if (ni * 16 + lhi * 4 + j > r0 + l4) s[ni][j] = -1e30f;
    }

    // --- online softmax, q = l4 lane-local; combine across lhi via 2 shfl ---
    float mloc = -1e30f;
    #pragma unroll
    for (int ni = 0; ni < 4; ++ni)
      #pragma unroll
      for (int j = 0; j < 4; ++j) mloc = fmaxf(mloc, s[ni][j]);
    mloc = fmaxf(mloc, __shfl_xor(mloc, 16));
    mloc = fmaxf(mloc, __shfl_xor(mloc, 32));
    float cscale = 1.f;
    if (!__all(mloc <= mrow + 8.f)) {   // T13 defer-max
      const float mnew = fmaxf(mrow, mloc);
      cscale = exp2f(mrow - mnew);
      #pragma unroll
      for (int j = 0; j < 4; ++j) {
        const float cj = __shfl(cscale, lhi * 4 + j);  // factor for row lhi*4+j
        #pragma unroll
        for (int di = 0; di < 4; ++di) oa[di][j] *= cj;
      }
      mrow = mnew;
    }
    float ssum = 0.f;
    #pragma unroll
    for (int ni = 0; ni < 4; ++ni)
      #pragma unroll
      for (int j = 0; j < 4; ++j) {
        const float pv = exp2f(s[ni][j] - mrow);
        s[ni][j] = pv;
        ssum += pv;
      }
    ssum += __shfl_xor(ssum, 16);
    ssum += __shfl_xor(ssum, 32);
    lrow = lrow * cscale + ssum;

    // --- P -> wave-private LDS: P[q=l4][t=ni*16+lhi*4+j], swizzled ---
    #pragma unroll
    for (int ni = 0; ni < 4; ++ni)
      #pragma unroll
      for (int j = 0; j < 4; ++j) {
        const int c = ni * 16 + lhi * 4 + j;
        Ps[wid][l4 * 64 + (((c >> 3) ^ (l4 & 7)) * 8) + (c & 7)] = (__bf16)s[ni][j];
      }

    // --- PV: O(16x64) += P(16x64) * V(64x64), B-operand = Vt rows (d) ---
    __builtin_amdgcn_s_setprio(1);
    #pragma unroll
    for (int kk = 0; kk < 2; ++kk) {
      const int ck = kk * 4 + lhi;    // chunk along t
      const bf16x8 ap = *(const bf16x8*)&Ps[wid][l4 * 64 + ((ck ^ (l4 & 7)) * 8)];
      #pragma unroll
      for (int di = 0; di < 4; ++di) {
        const int d = di * 16 + l4;
        const bf16x8 bv = *(const bf16x8*)&Vt[d * 64 + ((ck ^ (d & 7) ^ ((d >> 3) & 7)) * 8)];
        oa[di] = __builtin_amdgcn_mfma_f32_16x16x32_bf16(ap, bv, oa[di], 0, 0, 0);
      }
    }
    __builtin_amdgcn_s_setprio(0);
  }

  // epilogue: normalize and store bf16 (row q = r0 + lhi*4 + j, col = di*16+l4)
  #pragma unroll
  for (int j = 0; j < 4; ++j) {
    const float lj = __shfl(lrow, lhi * 4 + j);
    const float inv = 1.f / lj;
    const size_t row = (size_t)(b * S_) + qbase + r0 + lhi * 4 + j;
    #pragma unroll
    for (int di = 0; di < 4; ++di)
      o[row * 1024 + h * 64 + di * 16 + l4] = __float2bfloat16(oa[di][j] * inv);
  }
}

// ---------------------------------------------------------------------------
extern "C" void kernel_launch(void* const* d_in, const int* in_sizes, int n_in,
                              void* d_out, int out_size, void* d_ws, size_t ws_size,
                              hipStream_t stream)
{
  (void)in_sizes; (void)n_in; (void)out_size; (void)ws_size;
  const int*   idx  = (const int*)  d_in[0];
  const float* tok  = (const float*)d_in[1];
  const float* pos  = (const float*)d_in[2];
  const float* wq   = (const float*)d_in[3];
  const float* wk   = (const float*)d_in[4];
  const float* wv   = (const float*)d_in[5];
  const float* wo   = (const float*)d_in[6];
  const float* w1   = (const float*)d_in[7];
  const float* b1   = (const float*)d_in[8];
  const float* w2   = (const float*)d_in[9];
  const float* b2   = (const float*)d_in[10];
  const float* ln1g = (const float*)d_in[11];
  const float* ln1b = (const float*)d_in[12];
  const float* ln2g = (const float*)d_in[13];
  const float* ln2b = (const float*)d_in[14];
  const float* lnfg = (const float*)d_in[15];
  const float* lnfb = (const float*)d_in[16];
  const float* lmw  = (const float*)d_in[17];
  const float* lmb  = (const float*)d_in[18];
  float* out = (float*)d_out;

  // workspace carve-up (~259 MB)
  char* ws = (char*)d_ws;
  size_t off = 0;
  auto alloc = [&](size_t bytes) {
    void* p = ws + off; off += (bytes + 255) & ~(size_t)255; return p;
  };
  bf_t*  qkvw = (bf_t*) alloc((size_t)L_ * 3072 * 1024 * 2);  // Bt [3072][1024] per layer
  bf_t*  wot  = (bf_t*) alloc((size_t)L_ * 1024 * 1024 * 2);  // Bt [1024][1024]
  bf_t*  w1t  = (bf_t*) alloc((size_t)L_ * 4096 * 1024 * 2);  // Bt [4096][1024]
  bf_t*  w2t  = (bf_t*) alloc((size_t)L_ * 1024 * 4096 * 2);  // Bt [1024][4096]
  bf_t*  lmwt = (bf_t*) alloc((size_t)V_ * 1024 * 2);         // Bt [32000][1024]
  float* x    = (float*)alloc((size_t)M_ * D_ * 4);
  bf_t*  hbuf = (bf_t*) alloc((size_t)M_ * D_ * 2);
  bf_t*  qkvb = (bf_t*) alloc((size_t)M_ * 3072 * 2);         // bf16 QKV activations
  bf_t*  attb = (bf_t*) alloc((size_t)M_ * D_ * 2);
  bf_t*  ffnb = (bf_t*) alloc((size_t)M_ * DFF_ * 2);
  // split-K partials (2 x 16 MB f32) alias the hbuf+qkvb region (33.5 MB):
  // hbuf is dead after QKV-GEMM / FFN1 consume it; qkvb dead after attention.
  float* Ppart = (float*)hbuf;
  const long PSTRIDE = (long)M_ * 1024;

  const dim3 tb(32, 8);
  // wq/wk/wv (L,H,D,64): per-(l,h) transpose [D,64]->[64,D] into qkvw rows {q|k|v}
  k_transpose_bf16<<<dim3(2, 32, L_*H_), tb, 0, stream>>>(
      wq, qkvw + 0 * 1024 * 1024, D_, 64,
      (long)H_*D_*64, (long)D_*64, (long)3*1024*1024, (long)64*1024, H_);
  k_transpose_bf16<<<dim3(2, 32, L_*H_), tb, 0, stream>>>(
      wk, qkvw + 1 * 1024 * 1024, D_, 64,
      (long)H_*D_*64, (long)D_*64, (long)3*1024*1024, (long)64*1024, H_);
  k_transpose_bf16<<<dim3(2, 32, L_*H_), tb, 0, stream>>>(
      wv, qkvw + 2 * 1024 * 1024, D_, 64,
      (long)H_*D_*64, (long)D_*64, (long)3*1024*1024, (long)64*1024, H_);
  k_transpose_bf16<<<dim3(32, 32, L_), tb, 0, stream>>>(
      wo, wot, 1024, 1024, (long)1024*1024, 0, (long)1024*1024, 0, 1);
  k_transpose_bf16<<<dim3(128, 32, L_), tb, 0, stream>>>(
      w1, w1t, 1024, 4096, (long)1024*4096, 0, (long)1024*4096, 0, 1);
  k_transpose_bf16<<<dim3(32, 128, L_), tb, 0, stream>>>(
      w2, w2t, 4096, 1024, (long)4096*1024, 0, (long)4096*1024, 0, 1);
  k_transpose_bf16<<<dim3(1000, 32, 1), tb, 0, stream>>>(
      lmw, lmwt, 1024, V_, 0, 0, 0, 0, 1);

  k_embed<<<M_, 256, 0, stream>>>(idx, tok, pos, x);

  for (int l = 0; l < L_; ++l) {
    k_ln<<<M_, 256, 0, stream>>>(x, ln1g + l * D_, ln1b + l * D_, hbuf);
    // QKV: [4096,1024] x [3072,1024]^T -> bf16
    k_gemm<false, false, true, false, 1><<<24 * 32, 256, 0, stream>>>(
        hbuf, qkvw + (size_t)l * 3072 * 1024, nullptr, qkvb, nullptr,
        3072, 24, 1024, 1024, 0);
    k_attn_mfma<<<dim3(S_ / 64, B_ * H_), 256, 0, stream>>>(qkvb, attb);
    // out-proj, split-K=2 -> partials, then combine into x (residual add)
    k_gemm<false, false, false, false, 2><<<2 * 8 * 32, 256, 0, stream>>>(
        attb, wot + (size_t)l * 1024 * 1024, Ppart, nullptr, nullptr,
        1024, 8, 1024, 512, PSTRIDE);
    k_combine<<<M_, 256, 0, stream>>>(x, Ppart, nullptr, 2, PSTRIDE);
    k_ln<<<M_, 256, 0, stream>>>(x, ln2g + l * D_, ln2b + l * D_, hbuf);
    // FFN1 + bias + relu -> bf16
    k_gemm<true, true, true, false, 1><<<32 * 32, 256, 0, stream>>>(
        hbuf, w1t + (size_t)l * 4096 * 1024, nullptr, ffnb, b1 + l * DFF_,
        4096, 32, 1024, 1024, 0);
    // FFN2, split-K=2 -> partials, then combine (+b2) into x (residual add)
    k_gemm<false, false, false, false, 2><<<2 * 8 * 32, 256, 0, stream>>>(
        ffnb, w2t + (size_t)l * 1024 * 4096, Ppart, nullptr, nullptr,
        1024, 8, 4096, 2048, PSTRIDE);
    k_combine<<<M_, 256, 0, stream>>>(x, Ppart, b2 + l * D_, 2, PSTRIDE);
  }

  k_ln<<<M_, 256, 0, stream>>>(x, lnfg, lnfb, hbuf);
  // LM head: [4096,1024] x [32000,1024]^T + lm_b -> logits f32 (nontemporal)
  k_gemm<true, false, false, true, 1><<<(V_ / 128) * 32, 256, 0, stream>>>(
      hbuf, lmwt, out, nullptr, lmb,
      V_, 250, 1024, 1024, 0);
}